// Round 9
// baseline (146.552 us; speedup 1.0000x reference)
//
#include <hip/hip_runtime.h>
#include <hip/hip_bf16.h>
#include <math.h>

#define IMG 512
#define TW 64                     // output tile width
#define TH 32                     // output tile height
#define NTX 8                     // 512/64
#define NTY 16                    // 512/32
#define NIMG 48                   // 16*3
#define TPB 12                    // tiles per block
#define NPBLK 512                 // blocks (= 2 per CU exactly; 512*12 = 6144 tiles)
#define NPIX (16LL * 3 * 512 * 512)

#define C1F 0.0001f
#define C2F 0.0009f

// R9 == R8 resubmission (R8 bench died to an infra/container failure with no
// dispatch data; kernel re-audited — barrier-per-iteration is race-free,
// LDS 59,136 B < 64 KB static limit, no API calls in launch, uniform loop).
//
// Multi-tile pipelined blocks. R0-R7 invariant: 45-48 us regardless of
// occupancy/barriers/forced-MLP — no variant ever overlapped staging with
// compute (1 tile per block => stage and compute phases can never overlap
// within a wave; inter-block overlap measurably doesn't happen). Fix: each
// block owns 12 tiles, double-buffered LDS, T3-minimal 2-phase loop:
//   [issue loads t+1] -> [compute t from buf cur (R1's proven 4ch bf16
//   path)] -> [convert+write t+1 into buf cur^1] -> barrier -> swap.
// Loads' only use is AFTER compute, so compiler sinking is harmless — the
// issue-to-use distance IS the compute phase. launch_bounds(256,2) gives a
// 256-VGPR budget so pressure never motivates de-pipelining (R5/R7 lesson).
// Bonus: B-fragments hoisted out of the loop; ONE reduction instead of 12;
// grid 512 = capacity-forced 2 blocks/CU, zero tail.
// Tripwires: WRITE_SIZE >> 1 MB = spill; dur ~47 with clean tripwires =
// overlap is not the wall -> declare pattern ceiling.
#define SROWS 42
#define SR 88

typedef __attribute__((ext_vector_type(4))) short short4v;
typedef __attribute__((ext_vector_type(8))) short short8;
typedef __attribute__((ext_vector_type(4))) float float4v;
typedef __attribute__((ext_vector_type(2))) unsigned uint2v;
typedef __attribute__((ext_vector_type(4))) unsigned uint4v;

// 16x16x16 bf16 MFMA (device-verified _1k builtin on gfx950; host parse stub).
__device__ __forceinline__ float4v mfma16(short4v a, short4v b, float4v c) {
#if defined(__HIP_DEVICE_COMPILE__)
    return __builtin_amdgcn_mfma_f32_16x16x16bf16_1k(a, b, c, 0, 0, 0);
#else
    return c;   // host stub — never executed
#endif
}

// Gaussian window (sigma=1.5, ws=11), normalized (double-derived literals).
#define GW0 0.00102838f
#define GW1 0.00759877f
#define GW2 0.03600077f
#define GW3 0.10936069f
#define GW4 0.21300539f
#define GW5 0.26601172f

__device__ __forceinline__ unsigned short f2bf(float f) {
    unsigned u = __builtin_bit_cast(unsigned, f);
    u += 0x7FFF + ((u >> 16) & 1);            // RNE
    return (unsigned short)(u >> 16);
}
__device__ __forceinline__ unsigned pk2(float a, float b) {
    __hip_bfloat162 h = __float22bfloat162_rn(make_float2(a, b));
    unsigned u;
    __builtin_memcpy(&u, &h, 4);
    return u;
}

#define BC4(U) __builtin_bit_cast(short4v, U)

// Tile coords from tile index TT (128 tiles per image: 8x16, all shifts).
#define TCOORD(TT, R00, C00A, XI, YI)                                          \
    {                                                                          \
        const int gid_ = gbase + (TT);                                         \
        XI = xg + ((size_t)(gid_ >> 7) * (IMG * IMG));                         \
        YI = yg + ((size_t)(gid_ >> 7) * (IMG * IMG));                         \
        R00  = ((gid_ >> 3) & 15) * TH - 5;                                    \
        C00A = (gid_ & 7) * TW - 8;                                            \
    }

// Load one staging unit (8 cols = 2 float4 per tensor), R1's proven
// whole-float4 OOB predication.
#define STAGE_LOAD(PR, G10, R00, C00A, XI, YI, X0, X1, Y0, Y1)                 \
    {                                                                          \
        const int gr_ = (R00) + (PR), gc_ = (C00A) + ((G10) << 3);             \
        const bool rk_ = (unsigned)gr_ < 512u;                                 \
        const int o_ = gr_ * IMG + gc_;                                        \
        if (rk_ && (unsigned)gc_ < 512u) {                                     \
            X0 = *(const float4*)((XI) + o_);                                  \
            Y0 = *(const float4*)((YI) + o_);                                  \
        }                                                                      \
        if (rk_ && (unsigned)(gc_ + 4) < 512u) {                               \
            X1 = *(const float4*)((XI) + o_ + 4);                              \
            Y1 = *(const float4*)((YI) + o_ + 4);                              \
        }                                                                      \
    }

// Convert + write one staging unit into buffer NB (4 channels: x, y,
// x^2+y^2, x*y — R1's exact math), with owned-region L1 fold.
#define STAGE_WRITE(NB, PR, G10, X0, X1, Y0, Y1)                               \
    {                                                                          \
        const int pc8_ = (G10) << 3;                                           \
        *(uint4v*)&sbuf[NB][0][PR][pc8_] = (uint4v){                           \
            pk2(X0.x, X0.y), pk2(X0.z, X0.w), pk2(X1.x, X1.y), pk2(X1.z, X1.w)};\
        *(uint4v*)&sbuf[NB][1][PR][pc8_] = (uint4v){                           \
            pk2(Y0.x, Y0.y), pk2(Y0.z, Y0.w), pk2(Y1.x, Y1.y), pk2(Y1.z, Y1.w)};\
        *(uint4v*)&sbuf[NB][2][PR][pc8_] = (uint4v){                           \
            pk2(fmaf(X0.x,X0.x,Y0.x*Y0.x), fmaf(X0.y,X0.y,Y0.y*Y0.y)),         \
            pk2(fmaf(X0.z,X0.z,Y0.z*Y0.z), fmaf(X0.w,X0.w,Y0.w*Y0.w)),         \
            pk2(fmaf(X1.x,X1.x,Y1.x*Y1.x), fmaf(X1.y,X1.y,Y1.y*Y1.y)),         \
            pk2(fmaf(X1.z,X1.z,Y1.z*Y1.z), fmaf(X1.w,X1.w,Y1.w*Y1.w))};        \
        *(uint4v*)&sbuf[NB][3][PR][pc8_] = (uint4v){                           \
            pk2(X0.x*Y0.x, X0.y*Y0.y), pk2(X0.z*Y0.z, X0.w*Y0.w),              \
            pk2(X1.x*Y1.x, X1.y*Y1.y), pk2(X1.z*Y1.z, X1.w*Y1.w)};             \
        if ((unsigned)((PR) - 5) <= 31u && (unsigned)((G10) - 1) <= 7u)        \
            l1_loc += fabsf(X0.x-Y0.x)+fabsf(X0.y-Y0.y)                        \
                    + fabsf(X0.z-Y0.z)+fabsf(X0.w-Y0.w)                        \
                    + fabsf(X1.x-Y1.x)+fabsf(X1.y-Y1.y)                        \
                    + fabsf(X1.z-Y1.z)+fabsf(X1.w-Y1.w);                       \
    }

// SSIM epilogue over one float4v set (accumulates across all tiles).
#define SSIM_ACC(M1, M2, EE, PP)                                               \
    _Pragma("unroll")                                                          \
    for (int r_ = 0; r_ < 4; ++r_) {                                           \
        float mu1 = (M1)[r_], mu2 = (M2)[r_];                                  \
        float e   = (EE)[r_], e12 = (PP)[r_];                                  \
        float p = mu1 * mu2;                                                   \
        float s = fmaf(mu1, mu1, mu2 * mu2);                                   \
        float num1 = fmaf(2.f, p, C1F);                                        \
        float num2 = fmaf(2.f, e12 - p, C2F);                                  \
        float den1 = s + C1F;                                                  \
        float den2 = (e - s) + C2F;                                            \
        ssim_loc = fmaf(num1 * num2,                                           \
                        __builtin_amdgcn_rcpf(den1 * den2), ssim_loc);         \
    }

// H-conv of one row-group from LDS buffer `cur` into 4 named uint2v (named
// scalars — R4-proven scratch-free form; rule #20 insurance under pressure).
#define HCONV(ROWE, DX, DY, DS, DP)                                            \
    {                                                                          \
        const int row_ = (ROWE);                                               \
        const int co_ = w * 16 + q * 8;                                        \
        short8 a_; float4v d_;                                                 \
        a_ = *(const short8*)&sbuf[cur][0][row_][co_];                         \
        d_ = __builtin_amdgcn_mfma_f32_16x16x32_bf16(a_, bh, zero4, 0, 0, 0);  \
        DX = (uint2v){pk2(d_[0], d_[1]), pk2(d_[2], d_[3])};                   \
        a_ = *(const short8*)&sbuf[cur][1][row_][co_];                         \
        d_ = __builtin_amdgcn_mfma_f32_16x16x32_bf16(a_, bh, zero4, 0, 0, 0);  \
        DY = (uint2v){pk2(d_[0], d_[1]), pk2(d_[2], d_[3])};                   \
        a_ = *(const short8*)&sbuf[cur][2][row_][co_];                         \
        d_ = __builtin_amdgcn_mfma_f32_16x16x32_bf16(a_, bh, zero4, 0, 0, 0);  \
        DS = (uint2v){pk2(d_[0], d_[1]), pk2(d_[2], d_[3])};                   \
        a_ = *(const short8*)&sbuf[cur][3][row_][co_];                         \
        d_ = __builtin_amdgcn_mfma_f32_16x16x32_bf16(a_, bh, zero4, 0, 0, 0);  \
        DP = (uint2v){pk2(d_[0], d_[1]), pk2(d_[2], d_[3])};                   \
    }

__global__ __launch_bounds__(256, 2)
void ssim_pipe_kernel(const float* __restrict__ xg, const float* __restrict__ yg,
                      float* __restrict__ partials) {
    // Double-buffered 4-channel bf16 panels: 2*4*42*88*2 = 59,136 B
    // -> 2 blocks/CU (capacity-forced exact balance at grid=512).
    __shared__ unsigned short sbuf[2][4][SROWS][SR];
    __shared__ unsigned short gwtbl[16];
    __shared__ float red[8];

    const int tid  = threadIdx.x;
    const int lane = tid & 63;
    const int w    = tid >> 6;        // wave 0..3 = colgroup
    const int q    = lane >> 4;       // quad 0..3
    const int n16  = lane & 15;

    // ---- bf16 Gaussian tap table ----
    if (tid < 16) {
        const float gwf[11] = {GW0, GW1, GW2, GW3, GW4, GW5, GW4, GW3, GW2, GW1, GW0};
        unsigned short v = 0;
        #pragma unroll
        for (int t = 0; t < 11; ++t)
            if (tid == t) v = f2bf(gwf[t]);
        gwtbl[tid] = v;
    }
    __syncthreads();

    // ---- B fragments, hoisted once for all 12 tiles ----
    // h (K=32): Bh[k][n] = g[k-n-3]; v: Bv0[k][n]=g[k-n], Bv1[k][n]=g[k+16-n]
    short8 bh;
    short4v bv0, bv1;
    {
        int baseh = q * 8 - n16 - 3;
        #pragma unroll
        for (int j = 0; j < 8; ++j)
            bh[j] = (short)gwtbl[min((unsigned)(baseh + j), 15u)];
        int base0 = q * 4 - n16, base1 = q * 4 + 16 - n16;
        #pragma unroll
        for (int j = 0; j < 4; ++j) {
            bv0[j] = (short)gwtbl[min((unsigned)(base0 + j), 15u)];
            bv1[j] = (short)gwtbl[min((unsigned)(base1 + j), 15u)];
        }
    }

    // ---- Staging geometry (fixed across tiles): 420 units, 2 per thread ----
    const int pr0 = tid / 10, g0 = tid - pr0 * 10;
    const int u1x = tid + 256;
    const int pr1 = u1x / 10, g1 = u1x - pr1 * 10;
    const bool has1 = (tid < 420 - 256);

    float l1_loc = 0.f, ssim_loc = 0.f;
    const int gbase = blockIdx.x * TPB;
    const float4 zf = make_float4(0.f, 0.f, 0.f, 0.f);
    const float4v zero4 = {0.f, 0.f, 0.f, 0.f};

    // ---- Prologue: stage tile 0 into buf 0 ----
    {
        const float *xi, *yi; int r00, c00a;
        TCOORD(0, r00, c00a, xi, yi)
        float4 X00=zf, X01=zf, Y00=zf, Y01=zf, X10=zf, X11=zf, Y10=zf, Y11=zf;
        STAGE_LOAD(pr0, g0, r00, c00a, xi, yi, X00, X01, Y00, Y01)
        if (has1) STAGE_LOAD(pr1, g1, r00, c00a, xi, yi, X10, X11, Y10, Y11)
        STAGE_WRITE(0, pr0, g0, X00, X01, Y00, Y01)
        if (has1) STAGE_WRITE(0, pr1, g1, X10, X11, Y10, Y11)
    }
    __syncthreads();

    int cur = 0;
    for (int t = 0; t < TPB; ++t) {
        const bool hn = (t + 1 < TPB);

        // ---- Phase A: issue next tile's loads (fly during compute) ----
        float4 X00=zf, X01=zf, Y00=zf, Y01=zf, X10=zf, X11=zf, Y10=zf, Y11=zf;
        if (hn) {
            const float *nxi, *nyi; int nr00, nc00a;
            TCOORD(t + 1, nr00, nc00a, nxi, nyi)
            STAGE_LOAD(pr0, g0, nr00, nc00a, nxi, nyi, X00, X01, Y00, Y01)
            if (has1) STAGE_LOAD(pr1, g1, nr00, nc00a, nxi, nyi, X10, X11, Y10, Y11)
        }

        // ---- Phase B: compute tile t from buf[cur] (R1's proven path) ----
        {
            uint2v d0x, d0y, d0s, d0p;      // rg0
            uint2v e1x, e1y, e1s, e1p;      // rg1
            uint2v f2x, f2y, f2s, f2p;      // rg2 (rows >41 clamp: zero v-taps)
            HCONV(n16,               d0x, d0y, d0s, d0p)
            HCONV(16 + n16,          e1x, e1y, e1s, e1p)
            HCONV(min(32 + n16, 41), f2x, f2y, f2s, f2p)

            {   // rgp = 0
                float4v am1 = mfma16(BC4(d0x), bv0, mfma16(BC4(e1x), bv1, zero4));
                float4v am2 = mfma16(BC4(d0y), bv0, mfma16(BC4(e1y), bv1, zero4));
                float4v ae  = mfma16(BC4(d0s), bv0, mfma16(BC4(e1s), bv1, zero4));
                float4v ap  = mfma16(BC4(d0p), bv0, mfma16(BC4(e1p), bv1, zero4));
                SSIM_ACC(am1, am2, ae, ap)
            }
            {   // rgp = 1
                float4v bm1 = mfma16(BC4(e1x), bv0, mfma16(BC4(f2x), bv1, zero4));
                float4v bm2 = mfma16(BC4(e1y), bv0, mfma16(BC4(f2y), bv1, zero4));
                float4v be  = mfma16(BC4(e1s), bv0, mfma16(BC4(f2s), bv1, zero4));
                float4v bp  = mfma16(BC4(e1p), bv0, mfma16(BC4(f2p), bv1, zero4));
                SSIM_ACC(bm1, bm2, be, bp)
            }
        }

        // ---- Phase C: convert + write next tile into buf[cur^1] ----
        // (All waves finished reading buf[cur^1] before the PREVIOUS
        //  barrier, so one barrier per iteration is race-free.)
        if (hn) {
            STAGE_WRITE(cur ^ 1, pr0, g0, X00, X01, Y00, Y01)
            if (has1) STAGE_WRITE(cur ^ 1, pr1, g1, X10, X11, Y10, Y11)
        }
        __syncthreads();
        cur ^= 1;
    }

    // ---- Block reduction (once, after all 12 tiles) ----
    #pragma unroll
    for (int off = 32; off > 0; off >>= 1) {
        ssim_loc += __shfl_down(ssim_loc, off);
        l1_loc   += __shfl_down(l1_loc, off);
    }
    if (lane == 0) {
        red[w] = ssim_loc;
        red[4 + w] = l1_loc;
    }
    __syncthreads();
    if (tid == 0) {
        float ss = red[0] + red[1] + red[2] + red[3];
        float ll = red[4] + red[5] + red[6] + red[7];
        partials[blockIdx.x] = ss;
        partials[NPBLK + blockIdx.x] = ll;
    }
}

__global__ __launch_bounds__(256)
void finalize_kernel(const float* __restrict__ partials, float* __restrict__ out) {
    __shared__ double rs[4], rl[4];
    const int tid = threadIdx.x;
    double ss = 0.0, ll = 0.0;
    for (int i = tid; i < NPBLK; i += 256) {
        ss += (double)partials[i];
        ll += (double)partials[NPBLK + i];
    }
    #pragma unroll
    for (int off = 32; off > 0; off >>= 1) {
        ss += __shfl_down(ss, off);
        ll += __shfl_down(ll, off);
    }
    int wave = tid >> 6, lane = tid & 63;
    if (lane == 0) { rs[wave] = ss; rl[wave] = ll; }
    __syncthreads();
    if (tid == 0) {
        double sst = rs[0] + rs[1] + rs[2] + rs[3];
        double llt = rl[0] + rl[1] + rl[2] + rl[3];
        double invn = 1.0 / (double)NPIX;
        out[0] = (float)(llt * invn + (1.0 - sst * invn));
    }
}

extern "C" void kernel_launch(void* const* d_in, const int* in_sizes, int n_in,
                              void* d_out, int out_size, void* d_ws, size_t ws_size,
                              hipStream_t stream) {
    const float* x = (const float*)d_in[0];   // outputs
    const float* y = (const float*)d_in[1];   // labels
    float* out = (float*)d_out;
    float* partials = (float*)d_ws;           // 2*NPBLK*4 = 4,096 B

    ssim_pipe_kernel<<<dim3(NPBLK), dim3(256), 0, stream>>>(x, y, partials);
    finalize_kernel<<<1, dim3(256), 0, stream>>>(partials, out);
}

// Round 10
// 129.483 us; speedup vs baseline: 1.1318x; 1.1318x over previous
//
#include <hip/hip_runtime.h>
#include <hip/hip_bf16.h>
#include <math.h>

#define IMG 512
#define TW 64                     // output tile width
#define TH 32                     // output tile height
#define NTX 8                     // 512/64
#define NTY 16                    // 512/32
#define NIMG 48                   // 16*3
#define NBLOCKS (NTX * NTY * NIMG)   // 6144
#define NPIX (16LL * 3 * 512 * 512)

#define C1F 0.0001f
#define C2F 0.0009f

// R10: global_load_lds f32 staging (guide Common-mistake #1 — never tried
// in R0-R9). R9's post-mortem inverted the convoy theory: delivered BW ==
// in-flight bytes / latency, and R1 (barrier convoy, ~107KB posted per
// block before drain) was best BECAUSE of its depth. This round maximizes
// depth at zero VGPR cost: stage RAW f32 x,y panels direct-to-LDS with
// __builtin_amdgcn_global_load_lds(16B): 7 fire-and-forget 1KB loads per
// wave, no VGPR round trip, no convert pass (the bulk of R1's 52%
// VALUBusy deleted). Conversion to bf16 + product channels moves into the
// H-conv fragment build from f32 LDS reads (R1's exact arithmetic =>
// identical numerics). One barrier drains all (compiler emits
// vmcnt(0)+lgkmcnt(0) before s_barrier — here that IS the single wanted
// drain). LDS 2*3584*4 = 28,672B -> 5 blocks/CU (20 waves).
// LDS dest of global_load_lds is wave-uniform base + lane*16 (m104/m108):
// chunk base is uniform, lane slots linear — our flat layout matches.
// Row stride 84 f32 (84%4==0: 16B granules never cross rows; bank spread
// (20*n16+8q) mod 32 => 2-lane aliasing = free per m136).
// Boundary blocks pre-zero exactly the NOT-loaded slots (disjoint => no
// race with async LDS writes, no extra barrier). Padding cols 80..83 and
// spare tail (row 42) are never read by compute.
// Tripwires: WRITE_SIZE >> 1MB = spill; absmax must stay 0.0078125.

#define SR 84                     // LDS row stride in floats
#define SROWS 42
#define CHUNKF 256                // floats per 1KB chunk (64 lanes * 4)
#define NCHUNK 14                 // ceil(42*84/256)
#define BUFFLOATS (NCHUNK * CHUNKF)   // 3584 (incl. spare tail)

typedef __attribute__((ext_vector_type(4))) short short4v;
typedef __attribute__((ext_vector_type(8))) short short8;
typedef __attribute__((ext_vector_type(4))) float float4v;
typedef __attribute__((ext_vector_type(2))) unsigned uint2v;
typedef __attribute__((ext_vector_type(4))) unsigned uint4v;

// 16x16x16 bf16 MFMA (device-verified _1k builtin on gfx950; host parse stub).
__device__ __forceinline__ float4v mfma16(short4v a, short4v b, float4v c) {
#if defined(__HIP_DEVICE_COMPILE__)
    return __builtin_amdgcn_mfma_f32_16x16x16bf16_1k(a, b, c, 0, 0, 0);
#else
    return c;   // host stub — never executed
#endif
}

// Async global->LDS 16B: lds dest = wave-uniform base + lane*16.
__device__ __forceinline__ void gl_lds16(const float* g, float* l) {
#if defined(__HIP_DEVICE_COMPILE__)
    __builtin_amdgcn_global_load_lds(
        (const __attribute__((address_space(1))) void*)g,
        (__attribute__((address_space(3))) void*)l, 16, 0, 0);
#else
    (void)g; (void)l;
#endif
}

// Gaussian window (sigma=1.5, ws=11), normalized (double-derived literals).
#define GW0 0.00102838f
#define GW1 0.00759877f
#define GW2 0.03600077f
#define GW3 0.10936069f
#define GW4 0.21300539f
#define GW5 0.26601172f

__device__ __forceinline__ unsigned short f2bf(float f) {
    unsigned u = __builtin_bit_cast(unsigned, f);
    u += 0x7FFF + ((u >> 16) & 1);            // RNE
    return (unsigned short)(u >> 16);
}
__device__ __forceinline__ unsigned pk2(float a, float b) {
    __hip_bfloat162 h = __float22bfloat162_rn(make_float2(a, b));
    unsigned u;
    __builtin_memcpy(&u, &h, 4);
    return u;
}

#define BC4(U) __builtin_bit_cast(short4v, U)

// H-conv of one row from the f32 panels: read 8 f32 of x and y, build the
// 4 bf16 channels in-register (R1's exact math), 4 MFMAs into named
// uint2v, owned-region L1 (q in {1,2}, srow in [5,36] — never clamped).
#define HCONV_F32(ROWE, SROWE, DX, DY, DS, DP)                                 \
    {                                                                          \
        const int srow_ = (SROWE);                                             \
        const int b_ = (ROWE) * SR + co;                                       \
        float4v x0 = *(const float4v*)&xb[b_];                                 \
        float4v x1 = *(const float4v*)&xb[b_ + 4];                             \
        float4v y0 = *(const float4v*)&yb[b_];                                 \
        float4v y1 = *(const float4v*)&yb[b_ + 4];                             \
        uint4v ux_ = (uint4v){pk2(x0[0], x0[1]), pk2(x0[2], x0[3]),            \
                              pk2(x1[0], x1[1]), pk2(x1[2], x1[3])};           \
        uint4v uy_ = (uint4v){pk2(y0[0], y0[1]), pk2(y0[2], y0[3]),            \
                              pk2(y1[0], y1[1]), pk2(y1[2], y1[3])};           \
        uint4v u2_ = (uint4v){                                                 \
            pk2(fmaf(x0[0],x0[0],y0[0]*y0[0]), fmaf(x0[1],x0[1],y0[1]*y0[1])), \
            pk2(fmaf(x0[2],x0[2],y0[2]*y0[2]), fmaf(x0[3],x0[3],y0[3]*y0[3])), \
            pk2(fmaf(x1[0],x1[0],y1[0]*y1[0]), fmaf(x1[1],x1[1],y1[1]*y1[1])), \
            pk2(fmaf(x1[2],x1[2],y1[2]*y1[2]), fmaf(x1[3],x1[3],y1[3]*y1[3]))};\
        uint4v u3_ = (uint4v){                                                 \
            pk2(x0[0]*y0[0], x0[1]*y0[1]), pk2(x0[2]*y0[2], x0[3]*y0[3]),      \
            pk2(x1[0]*y1[0], x1[1]*y1[1]), pk2(x1[2]*y1[2], x1[3]*y1[3])};     \
        float4v d_;                                                            \
        d_ = __builtin_amdgcn_mfma_f32_16x16x32_bf16(                          \
                 __builtin_bit_cast(short8, ux_), bh, zero4, 0, 0, 0);         \
        DX = (uint2v){pk2(d_[0], d_[1]), pk2(d_[2], d_[3])};                   \
        d_ = __builtin_amdgcn_mfma_f32_16x16x32_bf16(                          \
                 __builtin_bit_cast(short8, uy_), bh, zero4, 0, 0, 0);         \
        DY = (uint2v){pk2(d_[0], d_[1]), pk2(d_[2], d_[3])};                   \
        d_ = __builtin_amdgcn_mfma_f32_16x16x32_bf16(                          \
                 __builtin_bit_cast(short8, u2_), bh, zero4, 0, 0, 0);         \
        DS = (uint2v){pk2(d_[0], d_[1]), pk2(d_[2], d_[3])};                   \
        d_ = __builtin_amdgcn_mfma_f32_16x16x32_bf16(                          \
                 __builtin_bit_cast(short8, u3_), bh, zero4, 0, 0, 0);         \
        DP = (uint2v){pk2(d_[0], d_[1]), pk2(d_[2], d_[3])};                   \
        if ((unsigned)(q - 1) <= 1u && (unsigned)(srow_ - 5) <= 31u)           \
            l1_loc += fabsf(x0[0]-y0[0])+fabsf(x0[1]-y0[1])                    \
                    + fabsf(x0[2]-y0[2])+fabsf(x0[3]-y0[3])                    \
                    + fabsf(x1[0]-y1[0])+fabsf(x1[1]-y1[1])                    \
                    + fabsf(x1[2]-y1[2])+fabsf(x1[3]-y1[3]);                   \
    }

// SSIM epilogue over one float4v set.
#define SSIM_ACC(M1, M2, EE, PP)                                               \
    _Pragma("unroll")                                                          \
    for (int r_ = 0; r_ < 4; ++r_) {                                           \
        float mu1 = (M1)[r_], mu2 = (M2)[r_];                                  \
        float e   = (EE)[r_], e12 = (PP)[r_];                                  \
        float p = mu1 * mu2;                                                   \
        float s = fmaf(mu1, mu1, mu2 * mu2);                                   \
        float num1 = fmaf(2.f, p, C1F);                                        \
        float num2 = fmaf(2.f, e12 - p, C2F);                                  \
        float den1 = s + C1F;                                                  \
        float den2 = (e - s) + C2F;                                            \
        ssim_loc = fmaf(num1 * num2,                                           \
                        __builtin_amdgcn_rcpf(den1 * den2), ssim_loc);         \
    }

__global__ __launch_bounds__(256, 5)
void ssim_tile_kernel(const float* __restrict__ xg, const float* __restrict__ yg,
                      float* __restrict__ partials) {
    __shared__ float xb[BUFFLOATS];                 // 14,336 B
    __shared__ float yb[BUFFLOATS];                 // 14,336 B
    __shared__ unsigned short gwtbl[16];            // bf16 taps, [11..15]=0
    __shared__ float red[8];

    const int tid  = threadIdx.x;
    const int lane = tid & 63;
    const int w    = tid >> 6;        // wave 0..3 = colgroup
    const int q    = lane >> 4;       // quad 0..3
    const int n16  = lane & 15;

    const int img = blockIdx.z;
    const int r00  = blockIdx.y * TH - 5;   // global row of staged row 0
    const int c00a = blockIdx.x * TW - 8;   // global col of staged col 0
    const float* __restrict__ xi = xg + (size_t)img * (IMG * IMG);
    const float* __restrict__ yi = yg + (size_t)img * (IMG * IMG);

    // ---- bf16 Gaussian tap table ----
    if (tid < 16) {
        const float gwf[11] = {GW0, GW1, GW2, GW3, GW4, GW5, GW4, GW3, GW2, GW1, GW0};
        unsigned short v = 0;
        #pragma unroll
        for (int t = 0; t < 11; ++t)
            if (tid == t) v = f2bf(gwf[t]);
        gwtbl[tid] = v;
    }

    // ---- Issue ALL staging loads: 28 chunks of 1KB across 4 waves.
    //      Wave w: chunks w*7..w*7+6; chunk<14 -> xb, else yb. ----
    #pragma unroll
    for (int k = 0; k < 7; ++k) {
        const int ck = w * 7 + k;                 // wave-uniform
        const bool isx = (ck < NCHUNK);
        const int c = isx ? ck : ck - NCHUNK;     // wave-uniform
        const int o = c * CHUNKF + lane * 4;      // this lane's flat f32 slot
        const int row = o / SR;                   // 0..42 (42 = spare tail)
        const int col = o - row * SR;             // 0..83 (80..83 = padding)
        const int gr = r00 + row, gc = c00a + col;
        if (((unsigned)gr < 512u) & ((unsigned)gc < 512u)) {
            const float* src = (isx ? xi : yi) + (size_t)gr * IMG + gc;
            float* dstb = (isx ? xb : yb) + c * CHUNKF;   // wave-uniform base
            gl_lds16(src, dstb);
        }
    }

    // ---- Boundary blocks: zero exactly the NOT-loaded slots (disjoint
    //      from async LDS writes -> race-free, no barrier needed). ----
    const bool interior = ((unsigned)(blockIdx.x - 1) <= 5u) &
                          ((unsigned)(blockIdx.y - 1) <= 13u);
    if (!interior) {
        const float4v z4 = {0.f, 0.f, 0.f, 0.f};
        for (int o = tid * 4; o < BUFFLOATS; o += 1024) {
            int row = o / SR, col = o - row * SR;
            int gr = r00 + row, gc = c00a + col;
            if (!(((unsigned)gr < 512u) & ((unsigned)gc < 512u))) {
                *(float4v*)&xb[o] = z4;
                *(float4v*)&yb[o] = z4;
            }
        }
    }

    __syncthreads();   // compiler-emitted vmcnt(0)+lgkmcnt(0): the ONE drain

    // ---- B fragments from gwtbl (OOB index clamps to >=11 -> 0) ----
    short8 bh;
    short4v bv0, bv1;
    {
        int baseh = q * 8 - n16 - 3;
        #pragma unroll
        for (int j = 0; j < 8; ++j)
            bh[j] = (short)gwtbl[min((unsigned)(baseh + j), 15u)];
        int base0 = q * 4 - n16, base1 = q * 4 + 16 - n16;
        #pragma unroll
        for (int j = 0; j < 4; ++j) {
            bv0[j] = (short)gwtbl[min((unsigned)(base0 + j), 15u)];
            bv1[j] = (short)gwtbl[min((unsigned)(base1 + j), 15u)];
        }
    }

    // ---- H-conv from f32 panels (channels built in-register) ----
    const int co = w * 16 + q * 8;
    const float4v zero4 = {0.f, 0.f, 0.f, 0.f};
    float l1_loc = 0.f;
    uint2v d0x, d0y, d0s, d0p;      // rg0
    uint2v e1x, e1y, e1s, e1p;      // rg1
    uint2v f2x, f2y, f2s, f2p;      // rg2 (rows >41 clamp: zero v-taps)
    HCONV_F32(n16,               n16,      d0x, d0y, d0s, d0p)
    HCONV_F32(16 + n16,          16 + n16, e1x, e1y, e1s, e1p)
    HCONV_F32(min(32 + n16, 41), 32 + n16, f2x, f2y, f2s, f2p)

    // ---- V-conv: acc = D1[rgp]·Bv0 + D1[rgp+1]·Bv1 (chained x16 MFMAs) ----
    float ssim_loc = 0.f;
    {   // rgp = 0
        float4v am1 = mfma16(BC4(d0x), bv0, mfma16(BC4(e1x), bv1, zero4));
        float4v am2 = mfma16(BC4(d0y), bv0, mfma16(BC4(e1y), bv1, zero4));
        float4v ae  = mfma16(BC4(d0s), bv0, mfma16(BC4(e1s), bv1, zero4));
        float4v ap  = mfma16(BC4(d0p), bv0, mfma16(BC4(e1p), bv1, zero4));
        SSIM_ACC(am1, am2, ae, ap)
    }
    {   // rgp = 1
        float4v bm1 = mfma16(BC4(e1x), bv0, mfma16(BC4(f2x), bv1, zero4));
        float4v bm2 = mfma16(BC4(e1y), bv0, mfma16(BC4(f2y), bv1, zero4));
        float4v be  = mfma16(BC4(e1s), bv0, mfma16(BC4(f2s), bv1, zero4));
        float4v bp  = mfma16(BC4(e1p), bv0, mfma16(BC4(f2p), bv1, zero4));
        SSIM_ACC(bm1, bm2, be, bp)
    }

    // ---- Block reduction ----
    #pragma unroll
    for (int off = 32; off > 0; off >>= 1) {
        ssim_loc += __shfl_down(ssim_loc, off);
        l1_loc   += __shfl_down(l1_loc, off);
    }
    if (lane == 0) {
        red[w] = ssim_loc;
        red[4 + w] = l1_loc;
    }
    __syncthreads();
    if (tid == 0) {
        float ss = red[0] + red[1] + red[2] + red[3];
        float ll = red[4] + red[5] + red[6] + red[7];
        int bid = blockIdx.x + NTX * (blockIdx.y + NTY * blockIdx.z);
        partials[bid] = ss;
        partials[NBLOCKS + bid] = ll;
    }
}

__global__ __launch_bounds__(1024)
void finalize_kernel(const float* __restrict__ partials, float* __restrict__ out) {
    __shared__ double rs[16], rl[16];
    const int tid = threadIdx.x;
    double ss = 0.0, ll = 0.0;
    for (int i = tid; i < NBLOCKS; i += 1024) {
        ss += (double)partials[i];
        ll += (double)partials[NBLOCKS + i];
    }
    #pragma unroll
    for (int off = 32; off > 0; off >>= 1) {
        ss += __shfl_down(ss, off);
        ll += __shfl_down(ll, off);
    }
    int wave = tid >> 6, lane = tid & 63;
    if (lane == 0) { rs[wave] = ss; rl[wave] = ll; }
    __syncthreads();
    if (tid == 0) {
        double sst = 0.0, llt = 0.0;
        #pragma unroll
        for (int w = 0; w < 16; ++w) { sst += rs[w]; llt += rl[w]; }
        double invn = 1.0 / (double)NPIX;
        out[0] = (float)(llt * invn + (1.0 - sst * invn));
    }
}

extern "C" void kernel_launch(void* const* d_in, const int* in_sizes, int n_in,
                              void* d_out, int out_size, void* d_ws, size_t ws_size,
                              hipStream_t stream) {
    const float* x = (const float*)d_in[0];   // outputs
    const float* y = (const float*)d_in[1];   // labels
    float* out = (float*)d_out;
    float* partials = (float*)d_ws;           // 2*NBLOCKS*4 = 49,152 B

    dim3 grid(NTX, NTY, NIMG);
    ssim_tile_kernel<<<grid, dim3(256), 0, stream>>>(x, y, partials);
    finalize_kernel<<<1, dim3(1024), 0, stream>>>(partials, out);
}